// Round 9
// baseline (410.299 us; speedup 1.0000x reference)
//
#include <hip/hip_runtime.h>
#include <hip/hip_bf16.h>

typedef __bf16 bf16x8 __attribute__((ext_vector_type(8)));
typedef float  f32x4  __attribute__((ext_vector_type(4)));
typedef float  f32x2  __attribute__((ext_vector_type(2)));

#define BSZ 8192

// padded second-moment triangle layout: row t has ceil((9-t)/2) f32x2 slots.
// float index of M(t,u) = 2*base2[t] + (u-t); X[t] at 50+t; 59 floats total.
__device__ __constant__ int d_base2[9] = {0, 5, 9, 13, 16, 19, 21, 23, 24};

// ---------------- stats0 (packed 9x9 second-moment) + weight prep merged ----------------
__global__ __launch_bounds__(256) void k_stats0(const float* __restrict__ x,
                                                float* __restrict__ part0,
                                                const float* __restrict__ w1,
                                                const float* __restrict__ w2,
                                                __bf16* __restrict__ w1b,
                                                __bf16* __restrict__ w2b) {
    __shared__ float sred[4 * 59];
    const int tid = threadIdx.x;
    {   // merged prep
        int t = blockIdx.x * 256 + tid;
        if (t < 8192) {           // w1: 64 oc x 128 k
            int oc = t >> 7, k = t & 127, c = k & 31, d = k >> 5;
            w1b[t] = (__bf16)w1[oc * 128 + c * 4 + d];
        }
        if (t < 32768) {          // w2: 128 oc x 256 k
            int oc = t >> 8, k = t & 255, c = k & 63, d = k >> 6;
            w2b[t] = (__bf16)w2[oc * 256 + c * 4 + d];
        }
    }
    const int base2[9] = {0, 5, 9, 13, 16, 19, 21, 23, 24};
    const int rsz[9]   = {5, 4, 4, 3, 3, 2, 2, 1, 1};
    f32x2 a2[25];
    float ax[9];
#pragma unroll
    for (int i = 0; i < 25; i++) a2[i] = (f32x2){0.f, 0.f};
#pragma unroll
    for (int i = 0; i < 9; i++) ax[i] = 0.f;
    const int total = BSZ * 784;
    for (int p = blockIdx.x * 256 + tid; p < total; p += gridDim.x * 256) {
        int b = p / 784, pix = p - b * 784;
        int y = pix / 28, xx = pix - y * 28;
        const float* xb = x + (long)b * 784;
        float nv[9];
#pragma unroll
        for (int dy = 0; dy < 3; dy++) {
            int yy = y + dy - 1;
#pragma unroll
            for (int dx = 0; dx < 3; dx++) {
                int x2 = xx + dx - 1;
                nv[dy * 3 + dx] = (yy >= 0 && yy < 28 && x2 >= 0 && x2 < 28) ? xb[yy * 28 + x2] : 0.f;
            }
        }
#pragma unroll
        for (int t = 0; t < 9; t++) {
            float vt = nv[t];
            ax[t] += vt;
            f32x2 vv = {vt, vt};
#pragma unroll
            for (int pp2 = 0; pp2 < 5; pp2++) {
                if (pp2 < rsz[t]) {
                    int u = t + 2 * pp2;
                    f32x2 nn = {nv[u], (u + 1 < 9) ? nv[u + 1] : 0.f};
                    a2[base2[t] + pp2] = __builtin_elementwise_fma(vv, nn, a2[base2[t] + pp2]);
                }
            }
        }
    }
    float outv[59];
#pragma unroll
    for (int i = 0; i < 50; i++) outv[i] = a2[i >> 1][i & 1];
#pragma unroll
    for (int i = 0; i < 9; i++) outv[50 + i] = ax[i];
#pragma unroll
    for (int i = 0; i < 59; i++) {
        float v = outv[i];
        v += __shfl_xor(v, 1);  v += __shfl_xor(v, 2);  v += __shfl_xor(v, 4);
        v += __shfl_xor(v, 8);  v += __shfl_xor(v, 16); v += __shfl_xor(v, 32);
        outv[i] = v;
    }
    const int l = tid & 63, w = tid >> 6;
    if (l == 0) {
#pragma unroll
        for (int i = 0; i < 59; i++) sred[w * 59 + i] = outv[i];
    }
    __syncthreads();
    if (tid < 59)
        part0[blockIdx.x * 64 + tid] = sred[tid] + sred[59 + tid] + sred[118 + tid] + sred[177 + tid];
}

// finalize BN0 and fold into conv0 weights: abc0[pg*72 + tap*8 + j] = A0[c]*w0[c][tap],
// abc0[288 + c] = C0[c]
__global__ void k_fin0(const float* __restrict__ part0, const float* __restrict__ w0,
                       const float* __restrict__ g0, const float* __restrict__ be0,
                       float* __restrict__ abc0) {
    __shared__ float red[4 * 59];
    int t = threadIdx.x, c = t & 63, g = t >> 6;
    if (c < 59) {
        float acc = 0.f;
        for (int i = g; i < 1024; i += 4) acc += part0[i * 64 + c];
        red[g * 59 + c] = acc;
    }
    __syncthreads();
    if (t < 59) red[t] = red[t] + red[59 + t] + red[118 + t] + red[177 + t];
    __syncthreads();
    if (t < 32) {
        const int base2[9] = {0, 5, 9, 13, 16, 19, 21, 23, 24};
        float wv[9];
#pragma unroll
        for (int tap = 0; tap < 9; tap++) wv[tap] = w0[t * 9 + tap];
        float sum = 0.f, sq = 0.f;
#pragma unroll
        for (int ta = 0; ta < 9; ta++) {
            sum = fmaf(wv[ta], red[50 + ta], sum);
#pragma unroll
            for (int u = ta; u < 9; u++) {
                float coef = (u == ta) ? 1.f : 2.f;
                float Mv = red[2 * base2[ta] + (u - ta)];
                sq = fmaf(coef * wv[ta] * wv[u], Mv, sq);
            }
        }
        float cnt = (float)BSZ * 784.f;
        float mean = sum / cnt;
        float var = sq / cnt - mean * mean;
        float A = g0[t] * rsqrtf(var + 1e-5f);
#pragma unroll
        for (int tap = 0; tap < 9; tap++)
            abc0[(t >> 3) * 72 + tap * 8 + (t & 7)] = A * wv[tap];
        abc0[288 + t] = be0[t] - mean * A;
    }
}

// ---------------- fused conv0(+BN0 folded, packed fp32)+ReLU + MFMA conv1, 4 images/block ----------------
__global__ __launch_bounds__(256) void k_conv01(const float* __restrict__ x,
                                                const float* __restrict__ abc0,
                                                const __bf16* __restrict__ w1b,
                                                __bf16* __restrict__ h1,
                                                float* __restrict__ part1) {
    __shared__ float xs[30 * 30];     // zero-padded input
    __shared__ __attribute__((aligned(16))) __bf16 sAt[2][16 * 136];
    const int tid = threadIdx.x;
    // zero border (116 cells) once
    if (tid < 116) {
        int idx;
        if (tid < 30)      idx = tid;
        else if (tid < 60) idx = 29 * 30 + (tid - 30);
        else if (tid < 88) idx = (tid - 60 + 1) * 30;
        else               idx = (tid - 88 + 1) * 30 + 29;
        xs[idx] = 0.f;
    }
    // hoisted folded weights as f32x2 pairs (wave-uniform -> scalar regs)
    const int pgu = __builtin_amdgcn_readfirstlane(tid >> 6);
    const f32x2* wfp = (const f32x2*)(abc0 + pgu * 72);
    f32x2 wf2[36];
#pragma unroll
    for (int i = 0; i < 36; i++) wf2[i] = wfp[i];
    const f32x2* c2p = (const f32x2*)(abc0 + 288 + pgu * 8);
    f32x2 c2[4];
#pragma unroll
    for (int j = 0; j < 4; j++) c2[j] = c2p[j];

    // producer indices
    const int pi = tid & 15, pd = (tid >> 4) & 3;
    // consumer indices
    const int w = tid >> 6, l = tid & 63, q = l >> 4, n = l & 15;
    const int oc = w * 16 + n;
    bf16x8 fbv[4];
#pragma unroll
    for (int kc = 0; kc < 4; kc++)
        fbv[kc] = *(const bf16x8*)&w1b[oc * 128 + kc * 32 + q * 8];
    const f32x2 zero2 = {0.f, 0.f};

    for (int img = 0; img < 4; img++) {
        const int b = blockIdx.x * 4 + img;
        // stage interior via float4 (28 = 7 x 4, row-aligned)
        const f32x4* xb4 = (const f32x4*)(x + (long)b * 784);
        if (tid < 196) {
            int yy = tid / 7, xx4 = (tid - yy * 7) * 4;
            f32x4 v4 = xb4[tid];
            float* dst = &xs[(yy + 1) * 30 + xx4 + 1];
            dst[0] = v4[0]; dst[1] = v4[1]; dst[2] = v4[2]; dst[3] = v4[3];
        }
        __syncthreads();   // xs ready; also epoch-separates sAt reuse across images
        f32x2 st_s = zero2, st_q = zero2;
        __bf16* hb = h1 + (long)b * 12544 + (q * 4) * 64 + oc;
        for (int mt = 0; mt < 13; mt++) {
            // ---- produce tile mt into sAt[mt&1] (packed fp32 conv0) ----
            __bf16* dst = &sAt[mt & 1][pi * 136 + pd * 32 + pgu * 8];
            int m = mt * 16 + pi;
            bf16x8 pk;
            if (m < 196) {
                int my = m / 14, mx = m - my * 14;
                int y0 = my * 2 + (pd >> 1), x0 = mx * 2 + (pd & 1);
                float nv[9];
#pragma unroll
                for (int dy = 0; dy < 3; dy++)
#pragma unroll
                    for (int dx = 0; dx < 3; dx++)
                        nv[dy * 3 + dx] = xs[(y0 + dy) * 30 + x0 + dx];
                f32x2 a2[4];
#pragma unroll
                for (int j = 0; j < 4; j++) a2[j] = c2[j];
#pragma unroll
                for (int t = 0; t < 9; t++) {
                    f32x2 vv = {nv[t], nv[t]};
#pragma unroll
                    for (int j = 0; j < 4; j++)
                        a2[j] = __builtin_elementwise_fma(vv, wf2[t * 4 + j], a2[j]);
                }
#pragma unroll
                for (int j = 0; j < 4; j++) {
                    f32x2 mv = __builtin_elementwise_max(a2[j], zero2);
                    pk[2 * j]     = (__bf16)mv[0];
                    pk[2 * j + 1] = (__bf16)mv[1];
                }
            } else {
#pragma unroll
                for (int j = 0; j < 8; j++) pk[j] = (__bf16)0.0f;
            }
            *(bf16x8*)dst = pk;
            __syncthreads();
            // ---- consume tile mt ----
            const __bf16* sa = &sAt[mt & 1][n * 136 + q * 8];
            f32x4 acc = {0.f, 0.f, 0.f, 0.f};
#pragma unroll
            for (int kc = 0; kc < 4; kc++) {
                bf16x8 fav = *(const bf16x8*)&sa[kc * 32];
                acc = __builtin_amdgcn_mfma_f32_16x16x32_bf16(fav, fbv[kc], acc, 0, 0, 0);
            }
            bool valid = (mt < 12) | (q == 0);
            __bf16* hp = hb + mt * 16 * 64;
            float fv[4];
#pragma unroll
            for (int r = 0; r < 4; r++) {
                __bf16 hv = (__bf16)acc[r];
                if (valid) hp[r * 64] = hv;
                fv[r] = (float)hv;              // padded rows give 0 -> no stat effect
            }
            f32x2 f01 = {fv[0], fv[1]}, f23 = {fv[2], fv[3]};
            st_s = st_s + f01; st_s = st_s + f23;
            st_q = __builtin_elementwise_fma(f01, f01, st_q);
            st_q = __builtin_elementwise_fma(f23, f23, st_q);
        }
        float ssum = st_s[0] + st_s[1], ssq = st_q[0] + st_q[1];
        ssum += __shfl_xor(ssum, 16); ssum += __shfl_xor(ssum, 32);
        ssq  += __shfl_xor(ssq, 16);  ssq  += __shfl_xor(ssq, 32);
        if (l < 16) {
            part1[(long)oc * BSZ + b] = ssum;
            part1[(long)(64 + oc) * BSZ + b] = ssq;
        }
    }
}

// ---------------- fused per-channel column reduce + BN finalize ----------------
__global__ __launch_bounds__(256) void k_redfin(const float* __restrict__ part,
                                                const float* __restrict__ g,
                                                const float* __restrict__ be,
                                                float* __restrict__ abc,
                                                int C, float cnt) {
    __shared__ float s1[256], s2[256];
    const int c = blockIdx.x, tid = threadIdx.x;
    float a = 0.f, bq = 0.f;
    const float* p1 = part + (long)c * BSZ;
    const float* p2 = part + (long)(C + c) * BSZ;
    for (int i = tid; i < BSZ; i += 256) { a += p1[i]; bq += p2[i]; }
    s1[tid] = a; s2[tid] = bq;
    __syncthreads();
    for (int s = 128; s > 0; s >>= 1) {
        if (tid < s) { s1[tid] += s1[tid + s]; s2[tid] += s2[tid + s]; }
        __syncthreads();
    }
    if (tid == 0) {
        float mean = s1[0] / cnt;
        float var = s2[0] / cnt - mean * mean;
        float A = g[c] * rsqrtf(var + 1e-5f);
        abc[c] = A;
        abc[C + c] = be[c] - mean * A;
    }
}

// ---------------- conv2 MFMA (BN1+ReLU packed), 1 barrier/tile, dbuf zt, 4 images/block ----------------
// P(mt): store zt[mt&1] (tile mt-2) + produce sAt[mt&1]; B; C(mt): MFMA -> zt[mt&1] + stats.
// zt[i]: written C(mt), stored P(mt+2), overwritten C(mt+2) — separated by B(mt+1)/B(mt+2).
// alias: stores(tile mt-2) elem < (mt-1)*2048; loads(tile mt) elem >= 7168 (mt=2) / 10752 (mt=3).
__global__ __launch_bounds__(256) void k_conv2s(__bf16* __restrict__ h1,
                                                const __bf16* __restrict__ w2b,
                                                const float* __restrict__ abc1,
                                                float* __restrict__ part2) {
    __shared__ __attribute__((aligned(16))) __bf16 sAt[2][16 * 264];
    __shared__ __attribute__((aligned(16))) __bf16 zt[2][16 * 136];
    __shared__ float sbn1[128];
    const int tid = threadIdx.x;
    if (tid < 128) sbn1[tid] = abc1[tid];
    const int w = tid >> 6, l = tid & 63, q = l >> 4, n = l & 15;
    bf16x8 fbv[2][8];
#pragma unroll
    for (int ntl = 0; ntl < 2; ntl++) {
        int oc = (2 * w + ntl) * 16 + n;
#pragma unroll
        for (int kc = 0; kc < 8; kc++)
            fbv[ntl][kc] = *(const bf16x8*)&w2b[oc * 256 + kc * 32 + q * 8];
    }
    __syncthreads();   // sbn1 ready
    // hoisted BN1 pairs: producer channel base c = (tid&7)*8 (same for both chunks)
    const int cpb = (tid & 7) * 8;
    f32x2 A1p[4], C1p[4];
#pragma unroll
    for (int p = 0; p < 4; p++) {
        A1p[p] = (f32x2){sbn1[cpb + 2 * p], sbn1[cpb + 2 * p + 1]};
        C1p[p] = (f32x2){sbn1[64 + cpb + 2 * p], sbn1[64 + cpb + 2 * p + 1]};
    }
    const f32x2 zero2 = {0.f, 0.f};
    const int srow = tid >> 4, so = (tid & 15) * 8;   // z2 store mapping

    for (int img = 0; img < 4; img++) {
        const int b = blockIdx.x * 4 + img;
        __bf16* src = h1 + (long)b * 12544;
        f32x2 st_s[2] = {zero2, zero2}, st_q[2] = {zero2, zero2};
        for (int mt = 0; mt < 4; mt++) {
            // ---- P: store tile mt-2 from zt[mt&1] ----
            if (mt >= 2) {
                int m = (mt - 2) * 16 + srow;
                if (m < 49) {
                    bf16x8 zv = *(const bf16x8*)&zt[mt & 1][srow * 136 + so];
                    *(bf16x8*)&src[m * 128 + so] = zv;
                }
            }
            // ---- P: produce sAt[mt&1] ----
#pragma unroll
            for (int it = 0; it < 2; it++) {
                int idx = it * 256 + tid;
                int rl = idx >> 5, o = (idx & 31) * 8;
                int r = mt * 16 + rl;
                bf16x8 wv;
                if (r < 49) {
                    int d = o >> 6;
                    int c = o & 63;
                    int py = r / 7, px = r - py * 7;
                    int msrc = (2 * py + (d >> 1)) * 14 + 2 * px + (d & 1);
                    bf16x8 v = *(const bf16x8*)&src[msrc * 64 + c];
#pragma unroll
                    for (int p = 0; p < 4; p++) {
                        f32x2 vf = {(float)v[2 * p], (float)v[2 * p + 1]};
                        f32x2 rr = __builtin_elementwise_fma(vf, A1p[p], C1p[p]);
                        rr = __builtin_elementwise_max(rr, zero2);
                        wv[2 * p]     = (__bf16)rr[0];
                        wv[2 * p + 1] = (__bf16)rr[1];
                    }
                } else {
#pragma unroll
                    for (int j = 0; j < 8; j++) wv[j] = (__bf16)0.0f;
                }
                *(bf16x8*)&sAt[mt & 1][rl * 264 + o] = wv;
            }
            __syncthreads();
            // ---- C: MFMA tile mt -> zt[mt&1] + stats ----
            bf16x8 fav[8];
#pragma unroll
            for (int kc = 0; kc < 8; kc++)
                fav[kc] = *(const bf16x8*)&sAt[mt & 1][n * 264 + kc * 32 + q * 8];
#pragma unroll
            for (int ntl = 0; ntl < 2; ntl++) {
                f32x4 acc = {0.f, 0.f, 0.f, 0.f};
#pragma unroll
                for (int kc = 0; kc < 8; kc++)
                    acc = __builtin_amdgcn_mfma_f32_16x16x32_bf16(fav[kc], fbv[ntl][kc], acc, 0, 0, 0);
                float fv[4];
#pragma unroll
                for (int rr = 0; rr < 4; rr++) {
                    __bf16 hv = (__bf16)acc[rr];
                    zt[mt & 1][(q * 4 + rr) * 136 + (2 * w + ntl) * 16 + n] = hv;
                    fv[rr] = (float)hv;         // padded rows -> 0
                }
                f32x2 f01 = {fv[0], fv[1]}, f23 = {fv[2], fv[3]};
                st_s[ntl] = st_s[ntl] + f01; st_s[ntl] = st_s[ntl] + f23;
                st_q[ntl] = __builtin_elementwise_fma(f01, f01, st_q[ntl]);
                st_q[ntl] = __builtin_elementwise_fma(f23, f23, st_q[ntl]);
            }
        }
        __syncthreads();
        // ---- drain: tiles 2 (zt[0]) and 3 (zt[1]) ----
        {
            int m2 = 32 + srow;
            if (m2 < 49) {
                bf16x8 zv = *(const bf16x8*)&zt[0][srow * 136 + so];
                *(bf16x8*)&src[m2 * 128 + so] = zv;
            }
            int m3 = 48 + srow;
            if (m3 < 49) {
                bf16x8 zv = *(const bf16x8*)&zt[1][srow * 136 + so];
                *(bf16x8*)&src[m3 * 128 + so] = zv;
            }
        }
#pragma unroll
        for (int ntl = 0; ntl < 2; ntl++) {
            float ssum = st_s[ntl][0] + st_s[ntl][1];
            float ssq  = st_q[ntl][0] + st_q[ntl][1];
            ssum += __shfl_xor(ssum, 16); ssum += __shfl_xor(ssum, 32);
            ssq  += __shfl_xor(ssq, 16);  ssq  += __shfl_xor(ssq, 32);
            if (l < 16) {
                int oc = (2 * w + ntl) * 16 + l;
                part2[(long)oc * BSZ + b] = ssum;
                part2[(long)(128 + oc) * BSZ + b] = ssq;
            }
        }
    }
}

// ---------------- light epilogue: BN2(packed) + ReLU + avgpool + FC from z2, 4 images/block ----------------
__global__ __launch_bounds__(256) void k_final(const __bf16* __restrict__ z2,
                                               const float* __restrict__ abc2,
                                               const float* __restrict__ wfc,
                                               const float* __restrict__ bfc,
                                               float* __restrict__ out) {
    __shared__ float sbn2[256];
    __shared__ float pp[16 * 128];
    __shared__ float pooled[128];
    __shared__ float fcred[80];
    const int tid = threadIdx.x;
    sbn2[tid] = abc2[tid];
    __syncthreads();
    const int g = tid & 15, c0 = g * 8, rg = tid >> 4;
    f32x2 A2p[4], C2p[4];
#pragma unroll
    for (int p = 0; p < 4; p++) {
        A2p[p] = (f32x2){sbn2[c0 + 2 * p], sbn2[c0 + 2 * p + 1]};
        C2p[p] = (f32x2){sbn2[128 + c0 + 2 * p], sbn2[128 + c0 + 2 * p + 1]};
    }
    const f32x2 zero2 = {0.f, 0.f};
    for (int img = 0; img < 4; img++) {
        const int b = blockIdx.x * 4 + img;
        const __bf16* src = z2 + (long)b * 12544;
        f32x2 acc2[4];
#pragma unroll
        for (int p = 0; p < 4; p++) acc2[p] = zero2;
        for (int rr = rg; rr < 49; rr += 16) {
            bf16x8 v = *(const bf16x8*)&src[rr * 128 + c0];
#pragma unroll
            for (int p = 0; p < 4; p++) {
                f32x2 vf = {(float)v[2 * p], (float)v[2 * p + 1]};
                f32x2 t0 = __builtin_elementwise_fma(vf, A2p[p], C2p[p]);
                t0 = __builtin_elementwise_max(t0, zero2);
                acc2[p] = acc2[p] + t0;
            }
        }
        f32x4 lo = {acc2[0][0], acc2[0][1], acc2[1][0], acc2[1][1]};
        f32x4 hi = {acc2[2][0], acc2[2][1], acc2[3][0], acc2[3][1]};
        *(f32x4*)&pp[rg * 128 + c0]     = lo;
        *(f32x4*)&pp[rg * 128 + c0 + 4] = hi;
        __syncthreads();
        if (tid < 128) {
            float s = 0.f;
#pragma unroll
            for (int r = 0; r < 16; r++) s += pp[r * 128 + tid];
            pooled[tid] = s * (1.f / 49.f);
        }
        __syncthreads();
        if (tid < 80) {
            int o = tid >> 3, s = tid & 7;
            float a = 0.f;
#pragma unroll
            for (int j = 0; j < 16; j++) a = fmaf(pooled[s * 16 + j], wfc[o * 128 + s * 16 + j], a);
            fcred[tid] = a;
        }
        __syncthreads();
        if (tid < 10) {
            float a = bfc[tid];
#pragma unroll
            for (int s = 0; s < 8; s++) a += fcred[tid * 8 + s];
            out[(long)b * 10 + tid] = a;
        }
    }
}

extern "C" void kernel_launch(void* const* d_in, const int* in_sizes, int n_in,
                              void* d_out, int out_size, void* d_ws, size_t ws_size,
                              hipStream_t stream) {
    const float* x   = (const float*)d_in[0];
    const float* w0  = (const float*)d_in[1];
    const float* g0  = (const float*)d_in[3];
    const float* be0 = (const float*)d_in[4];
    const float* w1  = (const float*)d_in[5];
    const float* g1  = (const float*)d_in[7];
    const float* be1 = (const float*)d_in[8];
    const float* w2  = (const float*)d_in[9];
    const float* g2  = (const float*)d_in[11];
    const float* be2 = (const float*)d_in[12];
    const float* wfc = (const float*)d_in[13];
    const float* bfc = (const float*)d_in[14];
    float* out = (float*)d_out;

    float* ws    = (float*)d_ws;
    float* part0 = ws;                       // 1024*64
    float* abc0  = part0 + 1024 * 64;        // 320 (folded w + C0)
    float* part1 = abc0 + 320;               // 128*8192
    float* abc1  = part1 + 128 * BSZ;        // 128
    float* part2 = abc1 + 128;               // 256*8192
    float* abc2  = part2 + 256 * BSZ;        // 256
    __bf16* w1b  = (__bf16*)(abc2 + 256);    // 8192
    __bf16* w2b  = w1b + 8192;               // 32768
    __bf16* h1   = w2b + 32768;              // 8192*12544 bf16 (~205 MB); z2 aliased per-image

    k_stats0<<<dim3(1024), dim3(256), 0, stream>>>(x, part0, w1, w2, w1b, w2b);
    k_fin0<<<dim3(1), dim3(256), 0, stream>>>(part0, w0, g0, be0, abc0);
    k_conv01<<<dim3(BSZ / 4), dim3(256), 0, stream>>>(x, abc0, w1b, h1, part1);
    k_redfin<<<dim3(64), dim3(256), 0, stream>>>(part1, g1, be1, abc1, 64, (float)(BSZ * 196));
    k_conv2s<<<dim3(BSZ / 4), dim3(256), 0, stream>>>(h1, w2b, abc1, part2);
    k_redfin<<<dim3(128), dim3(256), 0, stream>>>(part2, g2, be2, abc2, 128, (float)(BSZ * 49));
    k_final<<<dim3(BSZ / 4), dim3(256), 0, stream>>>(h1, abc2, wfc, bfc, out);
}